// Round 1
// baseline (635.065 us; speedup 1.0000x reference)
//
#include <hip/hip_runtime.h>
#include <hip/hip_bf16.h>
#include <math.h>

#define NS 4
#define HDIM 1024
#define DDIM 4096           // NS*HDIM
#define MDIM 24             // (2+NS)*NS
#define T 4                 // tokens per block
#define NTH 256
#define HC_EPS_F 1e-6f
#define NORM_EPS_F 1e-6f

__launch_bounds__(NTH, 2)
__global__ void mhc_fused(const float* __restrict__ x,
                          const float* __restrict__ hc_fn,
                          const float* __restrict__ hc_scale,
                          const float* __restrict__ hc_base,
                          float* __restrict__ out) {
  // 32 KB half-buffer of x (two passes over d), plus small scratch.
  __shared__ float xs[T][DDIM / 2];
  __shared__ float w_s[MDIM][T];
  __shared__ float ss_s[T];
  __shared__ float hpre_s[T][NS];
  __shared__ float hpost_s[T][NS];
  __shared__ float hres_s[T][NS][NS];

  const int tid  = threadIdx.x;
  const int lane = tid & 63;
  const int wave = tid >> 6;
  const long long tok0 = (long long)blockIdx.x * T;

  // ---- load all of this block's x into registers (fully coalesced float4) ----
  // xr[tt][p] holds d = p*1024 + tid*4 .. +3  == stream p, h = tid*4 .. +3
  float4 xr[T][4];
  #pragma unroll
  for (int tt = 0; tt < T; ++tt) {
    const float4* src = (const float4*)(x + (tok0 + tt) * DDIM);
    #pragma unroll
    for (int p = 0; p < 4; ++p) xr[tt][p] = src[p * NTH + tid];
  }

  // ---- Phase B: 24 dot products + sumsq. Wave w owns m in [6w, 6w+6). ----
  const int mb = wave * 6;
  float acc[6][T];
  float ssq[T];
  #pragma unroll
  for (int m = 0; m < 6; ++m)
    #pragma unroll
    for (int tt = 0; tt < T; ++tt) acc[m][tt] = 0.f;
  #pragma unroll
  for (int tt = 0; tt < T; ++tt) ssq[tt] = 0.f;

  #pragma unroll
  for (int half = 0; half < 2; ++half) {
    if (half) __syncthreads();           // previous half's reads done before overwrite
    #pragma unroll
    for (int tt = 0; tt < T; ++tt) {
      ((float4*)xs[tt])[tid]       = xr[tt][2 * half];
      ((float4*)xs[tt])[NTH + tid] = xr[tt][2 * half + 1];
    }
    __syncthreads();

    for (int it = 0; it < 8; ++it) {     // 512 float4 per half / 64 lanes
      const int fl = it * 64 + lane;
      float4 fnv[6];
      #pragma unroll
      for (int m = 0; m < 6; ++m)
        fnv[m] = ((const float4*)(hc_fn + (long long)(mb + m) * DDIM))[half * 512 + fl];
      #pragma unroll
      for (int tt = 0; tt < T; ++tt) {
        const float4 xv = ((const float4*)xs[tt])[fl];
        ssq[tt] = fmaf(xv.x, xv.x, fmaf(xv.y, xv.y, fmaf(xv.z, xv.z, fmaf(xv.w, xv.w, ssq[tt]))));
        #pragma unroll
        for (int m = 0; m < 6; ++m)
          acc[m][tt] = fmaf(xv.x, fnv[m].x,
                       fmaf(xv.y, fnv[m].y,
                       fmaf(xv.z, fnv[m].z,
                       fmaf(xv.w, fnv[m].w, acc[m][tt]))));
      }
    }
  }

  // ---- wave-level reduction of the 24 partials (+ sumsq from wave 0) ----
  #pragma unroll
  for (int m = 0; m < 6; ++m)
    #pragma unroll
    for (int tt = 0; tt < T; ++tt) {
      float v = acc[m][tt];
      #pragma unroll
      for (int off = 32; off > 0; off >>= 1) v += __shfl_xor(v, off, 64);
      if (lane == 0) w_s[mb + m][tt] = v;
    }
  if (wave == 0) {
    #pragma unroll
    for (int tt = 0; tt < T; ++tt) {
      float v = ssq[tt];
      #pragma unroll
      for (int off = 32; off > 0; off >>= 1) v += __shfl_xor(v, off, 64);
      if (lane == 0) ss_s[tt] = v;
    }
  }
  __syncthreads();

  // ---- Phase C: per-token gates + sinkhorn, one wave, lane = tt*16 + i*4 + j ----
  if (wave == 0) {
    const int tt = lane >> 4;
    const int e  = lane & 15;
    const int i  = e >> 2;
    const int j  = e & 3;
    const float rs = rsqrtf(ss_s[tt] * (1.0f / DDIM) + NORM_EPS_F);

    const float s2 = hc_scale[2];
    float h = w_s[8 + e][tt] * rs * s2 + hc_base[8 + e];

    // softmax over j (lanes xor 1,2), then + eps
    float mx = h;
    mx = fmaxf(mx, __shfl_xor(mx, 1, 64));
    mx = fmaxf(mx, __shfl_xor(mx, 2, 64));
    float ex = expf(h - mx);
    float sm = ex;
    sm += __shfl_xor(sm, 1, 64);
    sm += __shfl_xor(sm, 2, 64);
    h = ex / sm + HC_EPS_F;
    // column normalize: sum over i (lanes xor 4,8)
    float cs = h;
    cs += __shfl_xor(cs, 4, 64);
    cs += __shfl_xor(cs, 8, 64);
    h = h / (cs + HC_EPS_F);
    for (int itn = 0; itn < 19; ++itn) {
      float rsum = h;
      rsum += __shfl_xor(rsum, 1, 64);
      rsum += __shfl_xor(rsum, 2, 64);
      h = h / (rsum + HC_EPS_F);
      float csum = h;
      csum += __shfl_xor(csum, 4, 64);
      csum += __shfl_xor(csum, 8, 64);
      h = h / (csum + HC_EPS_F);
    }
    hres_s[tt][i][j] = h;

    if (e < NS) {
      const float s0 = hc_scale[0];
      const float s1 = hc_scale[1];
      const float wp = w_s[e][tt] * rs;
      hpre_s[tt][e] = 1.0f / (1.0f + expf(-(wp * s0 + hc_base[e]))) + HC_EPS_F;
      const float wq = w_s[NS + e][tt] * rs;
      hpost_s[tt][e] = 2.0f / (1.0f + expf(-(wq * s1 + hc_base[NS + e])));
    }
  }
  __syncthreads();

  // ---- Phase D: out[tt][n][h] = h_post[n]*y[h] + sum_i h_res[i][n]*x[tt][i][h]
  //      y[h] = sum_i h_pre[i]*x[tt][i][h]; x comes straight from registers ----
  #pragma unroll
  for (int tt = 0; tt < T; ++tt) {
    float hp[NS], hq[NS], hr[NS][NS];
    #pragma unroll
    for (int i = 0; i < NS; ++i) {
      hp[i] = hpre_s[tt][i];
      hq[i] = hpost_s[tt][i];
      #pragma unroll
      for (int j = 0; j < NS; ++j) hr[i][j] = hres_s[tt][i][j];
    }
    float4 y;
    y.x = hp[0]*xr[tt][0].x + hp[1]*xr[tt][1].x + hp[2]*xr[tt][2].x + hp[3]*xr[tt][3].x;
    y.y = hp[0]*xr[tt][0].y + hp[1]*xr[tt][1].y + hp[2]*xr[tt][2].y + hp[3]*xr[tt][3].y;
    y.z = hp[0]*xr[tt][0].z + hp[1]*xr[tt][1].z + hp[2]*xr[tt][2].z + hp[3]*xr[tt][3].z;
    y.w = hp[0]*xr[tt][0].w + hp[1]*xr[tt][1].w + hp[2]*xr[tt][2].w + hp[3]*xr[tt][3].w;
    #pragma unroll
    for (int n = 0; n < NS; ++n) {
      float4 o;
      o.x = hq[n]*y.x + hr[0][n]*xr[tt][0].x + hr[1][n]*xr[tt][1].x + hr[2][n]*xr[tt][2].x + hr[3][n]*xr[tt][3].x;
      o.y = hq[n]*y.y + hr[0][n]*xr[tt][0].y + hr[1][n]*xr[tt][1].y + hr[2][n]*xr[tt][2].y + hr[3][n]*xr[tt][3].y;
      o.z = hq[n]*y.z + hr[0][n]*xr[tt][0].z + hr[1][n]*xr[tt][1].z + hr[2][n]*xr[tt][2].z + hr[3][n]*xr[tt][3].z;
      o.w = hq[n]*y.w + hr[0][n]*xr[tt][0].w + hr[1][n]*xr[tt][1].w + hr[2][n]*xr[tt][2].w + hr[3][n]*xr[tt][3].w;
      ((float4*)(out + ((tok0 + tt) * NS + n) * HDIM))[tid] = o;
    }
  }
}

extern "C" void kernel_launch(void* const* d_in, const int* in_sizes, int n_in,
                              void* d_out, int out_size, void* d_ws, size_t ws_size,
                              hipStream_t stream) {
  const float* x        = (const float*)d_in[0];
  const float* hc_fn    = (const float*)d_in[1];
  const float* hc_scale = (const float*)d_in[2];
  const float* hc_base  = (const float*)d_in[3];
  float* out = (float*)d_out;

  const int ntok = in_sizes[0] / DDIM;   // B*S = 8192
  const int grid = ntok / T;             // 2048
  mhc_fused<<<grid, NTH, 0, stream>>>(x, hc_fn, hc_scale, hc_base, out);
}

// Round 2
// 120.239 us; speedup vs baseline: 5.2817x; 5.2817x over previous
//
#include <hip/hip_runtime.h>
#include <math.h>

#define NS 4
#define HDIM 1024
#define DDIM 4096           // NS*HDIM
#define MDIM 24             // (2+NS)*NS
#define T 4                 // tokens per block
#define NTH 256
#define HC_EPS_F 1e-6f
#define NORM_EPS_F 1e-6f

// async global->LDS, 16B per lane. LDS dest is wave-uniform base + lane*16.
__device__ __forceinline__ void gload_lds16(const float* g, float* l) {
  __builtin_amdgcn_global_load_lds(
      (const __attribute__((address_space(1))) void*)g,
      (__attribute__((address_space(3))) void*)l, 16, 0, 0);
}

__launch_bounds__(NTH, 2)
__global__ void mhc_fused(const float* __restrict__ x,
                          const float* __restrict__ hc_fn,
                          const float* __restrict__ hc_scale,
                          const float* __restrict__ hc_base,
                          float* __restrict__ out) {
  __shared__ float xs[T][DDIM];        // 64 KB: full x for 4 tokens
  __shared__ float w_s[MDIM][T];
  __shared__ float ss_s[T];
  __shared__ float hpre_s[T][NS];
  __shared__ float hpost_s[T][NS];
  __shared__ float hres_s[T][NS][NS];

  const int tid  = threadIdx.x;
  const int lane = tid & 63;
  const int wave = tid >> 6;
  const long long tok0 = (long long)blockIdx.x * T;

  // ---- Phase A: stage x straight into LDS (no VGPR copy kept) ----
  // float4 slot (p*256 + tid) of token tt; each wave covers a contiguous
  // 64-float4 run so lds dst = wave-uniform base + lane*16.
  #pragma unroll
  for (int tt = 0; tt < T; ++tt) {
    const float* gsrc = x + (tok0 + tt) * DDIM;
    #pragma unroll
    for (int p = 0; p < 4; ++p) {
      gload_lds16(gsrc + (p * NTH + tid) * 4,
                  &xs[tt][(p * NTH + wave * 64) * 4]);
    }
  }
  __syncthreads();   // drains vmcnt

  // ---- Phase B: 24 dots + sumsq from LDS. Wave w owns m in [6w, 6w+6). ----
  const int mb = wave * 6;
  const float* fp0 = hc_fn + (long long)mb * DDIM;
  float acc[6][T];
  float ssq[T];
  #pragma unroll
  for (int m = 0; m < 6; ++m)
    #pragma unroll
    for (int tt = 0; tt < T; ++tt) acc[m][tt] = 0.f;
  #pragma unroll
  for (int tt = 0; tt < T; ++tt) ssq[tt] = 0.f;

  for (int it = 0; it < 16; ++it) {
    const int fl = it * 64 + lane;
    float4 fnv[6];
    #pragma unroll
    for (int m = 0; m < 6; ++m)
      fnv[m] = ((const float4*)(fp0 + (long long)m * DDIM))[fl];
    #pragma unroll
    for (int tt = 0; tt < T; ++tt) {
      const float4 xv = ((const float4*)xs[tt])[fl];
      ssq[tt] = fmaf(xv.x, xv.x, fmaf(xv.y, xv.y, fmaf(xv.z, xv.z, fmaf(xv.w, xv.w, ssq[tt]))));
      #pragma unroll
      for (int m = 0; m < 6; ++m)
        acc[m][tt] = fmaf(xv.x, fnv[m].x,
                     fmaf(xv.y, fnv[m].y,
                     fmaf(xv.z, fnv[m].z,
                     fmaf(xv.w, fnv[m].w, acc[m][tt]))));
    }
  }

  // ---- cross-lane reduction of the 24 partials (+ sumsq from wave 0) ----
  #pragma unroll
  for (int m = 0; m < 6; ++m)
    #pragma unroll
    for (int tt = 0; tt < T; ++tt) {
      float v = acc[m][tt];
      #pragma unroll
      for (int off = 32; off > 0; off >>= 1) v += __shfl_xor(v, off, 64);
      if (lane == 0) w_s[mb + m][tt] = v;
    }
  if (wave == 0) {
    #pragma unroll
    for (int tt = 0; tt < T; ++tt) {
      float v = ssq[tt];
      #pragma unroll
      for (int off = 32; off > 0; off >>= 1) v += __shfl_xor(v, off, 64);
      if (lane == 0) ss_s[tt] = v;
    }
  }
  __syncthreads();

  // ---- Phase C: gates + sinkhorn on wave 0; lane = tt*16 + i*4 + j ----
  if (wave == 0) {
    const int tt = lane >> 4;
    const int e  = lane & 15;
    const int i  = e >> 2;
    const int j  = e & 3;
    const float rs = rsqrtf(ss_s[tt] * (1.0f / DDIM) + NORM_EPS_F);

    const float s2 = hc_scale[2];
    float h = w_s[8 + e][tt] * rs * s2 + hc_base[8 + e];

    // softmax over j (xor 1,2), + eps
    float mx = h;
    mx = fmaxf(mx, __shfl_xor(mx, 1, 64));
    mx = fmaxf(mx, __shfl_xor(mx, 2, 64));
    float ex = expf(h - mx);
    float sm = ex;
    sm += __shfl_xor(sm, 1, 64);
    sm += __shfl_xor(sm, 2, 64);
    h = ex / sm + HC_EPS_F;
    // column normalize: sum over i (xor 4,8)
    float cs = h;
    cs += __shfl_xor(cs, 4, 64);
    cs += __shfl_xor(cs, 8, 64);
    h = h / (cs + HC_EPS_F);
    for (int itn = 0; itn < 19; ++itn) {
      float rsum = h;
      rsum += __shfl_xor(rsum, 1, 64);
      rsum += __shfl_xor(rsum, 2, 64);
      h = h / (rsum + HC_EPS_F);
      float csum = h;
      csum += __shfl_xor(csum, 4, 64);
      csum += __shfl_xor(csum, 8, 64);
      h = h / (csum + HC_EPS_F);
    }
    hres_s[tt][i][j] = h;

    if (e < NS) {
      const float s0 = hc_scale[0];
      const float s1 = hc_scale[1];
      const float wp = w_s[e][tt] * rs;
      hpre_s[tt][e] = 1.0f / (1.0f + expf(-(wp * s0 + hc_base[e]))) + HC_EPS_F;
      const float wq = w_s[NS + e][tt] * rs;
      hpost_s[tt][e] = 2.0f / (1.0f + expf(-(wq * s1 + hc_base[NS + e])));
    }
  }
  __syncthreads();

  // ---- Phase D: out[tt][n][h] = h_post[n]*y[h] + sum_i h_res[i][n]*x[i][h]
  //      y[h] = sum_i h_pre[i]*x[i][h]; x re-read from LDS ----
  #pragma unroll
  for (int tt = 0; tt < T; ++tt) {
    float hp[NS], hq[NS], hr[NS][NS];
    #pragma unroll
    for (int i = 0; i < NS; ++i) {
      hp[i] = hpre_s[tt][i];
      hq[i] = hpost_s[tt][i];
      #pragma unroll
      for (int j = 0; j < NS; ++j) hr[i][j] = hres_s[tt][i][j];
    }
    float4 xv[4];
    #pragma unroll
    for (int p = 0; p < 4; ++p) xv[p] = ((const float4*)xs[tt])[p * NTH + tid];

    float4 y;
    y.x = hp[0]*xv[0].x + hp[1]*xv[1].x + hp[2]*xv[2].x + hp[3]*xv[3].x;
    y.y = hp[0]*xv[0].y + hp[1]*xv[1].y + hp[2]*xv[2].y + hp[3]*xv[3].y;
    y.z = hp[0]*xv[0].z + hp[1]*xv[1].z + hp[2]*xv[2].z + hp[3]*xv[3].z;
    y.w = hp[0]*xv[0].w + hp[1]*xv[1].w + hp[2]*xv[2].w + hp[3]*xv[3].w;
    #pragma unroll
    for (int n = 0; n < NS; ++n) {
      float4 o;
      o.x = hq[n]*y.x + hr[0][n]*xv[0].x + hr[1][n]*xv[1].x + hr[2][n]*xv[2].x + hr[3][n]*xv[3].x;
      o.y = hq[n]*y.y + hr[0][n]*xv[0].y + hr[1][n]*xv[1].y + hr[2][n]*xv[2].y + hr[3][n]*xv[3].y;
      o.z = hq[n]*y.z + hr[0][n]*xv[0].z + hr[1][n]*xv[1].z + hr[2][n]*xv[2].z + hr[3][n]*xv[3].z;
      o.w = hq[n]*y.w + hr[0][n]*xv[0].w + hr[1][n]*xv[1].w + hr[2][n]*xv[2].w + hr[3][n]*xv[3].w;
      ((float4*)(out + ((tok0 + tt) * NS + n) * HDIM))[tid] = o;
    }
  }
}

extern "C" void kernel_launch(void* const* d_in, const int* in_sizes, int n_in,
                              void* d_out, int out_size, void* d_ws, size_t ws_size,
                              hipStream_t stream) {
  const float* x        = (const float*)d_in[0];
  const float* hc_fn    = (const float*)d_in[1];
  const float* hc_scale = (const float*)d_in[2];
  const float* hc_base  = (const float*)d_in[3];
  float* out = (float*)d_out;

  const int ntok = in_sizes[0] / DDIM;   // B*S = 8192
  const int grid = ntok / T;             // 2048
  mhc_fused<<<grid, NTH, 0, stream>>>(x, hc_fn, hc_scale, hc_base, out);
}